// Round 10
// baseline (309.334 us; speedup 1.0000x reference)
//
#include <hip/hip_runtime.h>
#include <hip/hip_bf16.h>
#include <hip/hip_cooperative_groups.h>

namespace cg = cooperative_groups;

#define N_NODES 50000
#define N_EDGES 800000
#define D 128
#define SCAN_NB 49  // ceil(50000/1024)

static_assert(N_NODES < 65536, "src must fit in 16 bits for epack");

typedef __attribute__((ext_vector_type(8))) short short8;
typedef __attribute__((ext_vector_type(4))) float f32x4;
typedef unsigned int uint;
typedef unsigned short ushort;

__device__ __forceinline__ ushort f2bf(float f) {
    // float -> bf16 bits, round-to-nearest-even
    uint u = __float_as_uint(f);
    u += 0x7fffu + ((u >> 16) & 1u);
    return (ushort)(u >> 16);
}

__device__ __forceinline__ float bflo(uint u) { return __uint_as_float(u << 16); }
__device__ __forceinline__ float bfhi(uint u) { return __uint_as_float(u & 0xffff0000u); }

// ---------------- prep: W fp32->bf16 AND zero deg (independent work) ----------------

__global__ __launch_bounds__(256) void sgcn_prep(
    const float* __restrict__ W, ushort* __restrict__ Wb, int* __restrict__ deg)
{
    int t = blockIdx.x * 256 + threadIdx.x;
    if (t < (D * D) / 4) {
        float4 a = reinterpret_cast<const float4*>(W)[t];
        ushort4 s;
        s.x = f2bf(a.x); s.y = f2bf(a.y); s.z = f2bf(a.z); s.w = f2bf(a.w);
        *reinterpret_cast<ushort4*>(Wb + (size_t)t * 4) = s;
    }
    if (t < N_NODES / 4) {  // 12500 int4 stores zero 50000 ints exactly
        reinterpret_cast<int4*>(deg)[t] = make_int4(0, 0, 0, 0);
    }
}

// ---------------- scan helper (shared by coop + fallback) ----------------
// Block b: off0 = sum(deg[0 .. b*1024)), then exclusive-scan of its 1024-chunk.

__device__ __forceinline__ void scan_block_body(
    const int* __restrict__ deg, int* __restrict__ rowptr, int b, int tid,
    int* part /* [256] shared */, int* soff /* [1] shared */)
{
    const int4* d4 = reinterpret_cast<const int4*>(deg);
    int pre = 0;
    for (int i = tid; i < b * 256; i += 256) {
        int4 v = d4[i];
        pre += v.x + v.y + v.z + v.w;
    }
    part[tid] = pre;
    __syncthreads();
    for (int off = 128; off > 0; off >>= 1) {
        if (tid < off) part[tid] += part[tid + off];
        __syncthreads();
    }
    if (tid == 0) *soff = part[0];
    __syncthreads();

    int base = b * 1024 + tid * 4;
    int4 v = make_int4(0, 0, 0, 0);
    if (base < N_NODES) v = *reinterpret_cast<const int4*>(deg + base);
    int s = v.x + v.y + v.z + v.w;
    part[tid] = s;
    __syncthreads();
    for (int off = 1; off < 256; off <<= 1) {
        int mine  = part[tid];
        int other = (tid >= off) ? part[tid - off] : 0;
        __syncthreads();
        part[tid] = mine + other;
        __syncthreads();
    }
    int run = *soff + ((tid == 0) ? 0 : part[tid - 1]);
    if (base < N_NODES) {
        int4 r;
        r.x = run;
        r.y = run + v.x;
        r.z = r.y + v.y;
        r.w = r.z + v.z;
        *reinterpret_cast<int4*>(rowptr + base) = r;
        if (base + 4 == N_NODES) rowptr[N_NODES] = r.w + v.w;
    }
}

// ---------------- Cooperative CSR build: hist -> scan -> permute ----------------

__global__ __launch_bounds__(256) void sgcn_csr(
    const int* __restrict__ src, const int* __restrict__ dst,
    const float* __restrict__ val, int* __restrict__ deg,
    int* __restrict__ rank, int* __restrict__ rowptr, uint* __restrict__ epack)
{
    cg::grid_group grid = cg::this_grid();
    __shared__ int part[256];
    __shared__ int soff;
    int tid = blockIdx.x * 256 + threadIdx.x;
    int stride = gridDim.x * 256;

    // Phase A: histogram + rank (deg pre-zeroed by sgcn_prep)
    for (int e = tid; e < N_EDGES; e += stride)
        rank[e] = atomicAdd(&deg[dst[e]], 1);
    grid.sync();

    // Phase B: exclusive scan -> rowptr (first SCAN_NB blocks)
    if (blockIdx.x < SCAN_NB)
        scan_block_body(deg, rowptr, blockIdx.x, threadIdx.x, part, &soff);
    grid.sync();

    // Phase C: permute into dst-sorted order, packed 4 B/edge
    for (int e = tid; e < N_EDGES; e += stride) {
        int pos = rowptr[dst[e]] + rank[e];
        epack[pos] = ((uint)f2bf(val[e]) << 16) | (uint)src[e];
    }
}

// ---------------- Fallback kernels (if coop launch unavailable) ----------------

__global__ __launch_bounds__(256) void sgcn_hist_rank(
    const int* __restrict__ dst, int* __restrict__ deg, int* __restrict__ rank)
{
    int e = blockIdx.x * 256 + threadIdx.x;
    if (e < N_EDGES)
        rank[e] = atomicAdd(&deg[dst[e]], 1);
}

__global__ __launch_bounds__(256) void sgcn_scanf(
    const int* __restrict__ deg, int* __restrict__ rowptr)
{
    __shared__ int part[256];
    __shared__ int soff;
    scan_block_body(deg, rowptr, blockIdx.x, threadIdx.x, part, &soff);
}

__global__ __launch_bounds__(256) void sgcn_permute(
    const int* __restrict__ src, const int* __restrict__ dst,
    const float* __restrict__ val, const int* __restrict__ rowptr,
    const int* __restrict__ rank, uint* __restrict__ epack)
{
    int e = blockIdx.x * 256 + threadIdx.x;
    if (e < N_EDGES) {
        int pos = rowptr[dst[e]] + rank[e];
        epack[pos] = ((uint)f2bf(val[e]) << 16) | (uint)src[e];
    }
}

// ---------------- MFMA GEMM first: y = x @ W^T (bf16 out) ----------------
// Wave: 16-row x 128-col stripe. A: lane holds x[m0+(l&15)][kb*8+j] (fp32 read,
// bf16 convert inline). B: lane holds W[nt*16+(l&15)][kb*8+j] (row-major Wb).
// C/D: col = l&15 (n), row = kb*4 + r (m). [m89 layout]

__global__ __launch_bounds__(256) void sgcn_gemm_y(
    const float* __restrict__ x, const ushort* __restrict__ Wb,
    ushort* __restrict__ y)
{
    int wave = threadIdx.x >> 6;
    int lane = threadIdx.x & 63;
    int lm = lane & 15;
    int kb = lane >> 4;

    short8 bfr[8][4];
#pragma unroll
    for (int nt = 0; nt < 8; ++nt)
#pragma unroll
        for (int kk = 0; kk < 4; ++kk)
            bfr[nt][kk] = *reinterpret_cast<const short8*>(
                Wb + (nt * 16 + lm) * D + kk * 32 + kb * 8);

    const int nMT = N_NODES / 16;  // 3125
    int mt0 = blockIdx.x * 4 + wave;
    int strideMT = gridDim.x * 4;
    for (int mt = mt0; mt < nMT; mt += strideMT) {
        int m0 = mt * 16;
        const float* xrow = x + (long)(m0 + lm) * D + kb * 8;
        short8 afr[4];
#pragma unroll
        for (int kk = 0; kk < 4; ++kk) {
            float4 a = *reinterpret_cast<const float4*>(xrow + kk * 32);
            float4 c = *reinterpret_cast<const float4*>(xrow + kk * 32 + 4);
            short8 s;
            s[0] = (short)f2bf(a.x); s[1] = (short)f2bf(a.y);
            s[2] = (short)f2bf(a.z); s[3] = (short)f2bf(a.w);
            s[4] = (short)f2bf(c.x); s[5] = (short)f2bf(c.y);
            s[6] = (short)f2bf(c.z); s[7] = (short)f2bf(c.w);
            afr[kk] = s;
        }
#pragma unroll
        for (int nt = 0; nt < 8; ++nt) {
            f32x4 acc = {0.f, 0.f, 0.f, 0.f};
#pragma unroll
            for (int kk = 0; kk < 4; ++kk)
                acc = __builtin_amdgcn_mfma_f32_16x16x32_bf16(afr[kk], bfr[nt][kk], acc, 0, 0, 0);
            ushort* yp = y + (long)(m0 + kb * 4) * D + nt * 16 + lm;
#pragma unroll
            for (int r = 0; r < 4; ++r)
                yp[(long)r * D] = f2bf(acc[r]);
        }
    }
}

// ---------------- Aggregation: ONE NODE PER QUARTER-WAVE ----------------
// yb rows = 64 uints (256 B). Quarter (16 lanes) owns one node; lane c reads
// uint4 at row*64 + c*4 (channels c*8..c*8+7). No shuffles — each lane's
// accumulators are complete. 4-edge unroll -> 4 rows in flight per quarter
// (16 per wave). 3125 blocks x 16 quarters = 50000 nodes exactly.

__global__ __launch_bounds__(256) void sgcn_aggregate(
    const uint* __restrict__ yb, const int* __restrict__ rowptr,
    const uint* __restrict__ ep, const float* __restrict__ bias,
    float* __restrict__ out)
{
    int n = (blockIdx.x * 256 + threadIdx.x) >> 4;  // exact: grid*16 == N_NODES
    int c = threadIdx.x & 15;
    float4 bv0 = *reinterpret_cast<const float4*>(bias + c * 8);
    float4 bv1 = *reinterpret_cast<const float4*>(bias + c * 8 + 4);

    int j0 = rowptr[n], j1 = rowptr[n + 1];
    float a0 = 0.f, a1 = 0.f, a2 = 0.f, a3 = 0.f;
    float a4 = 0.f, a5 = 0.f, a6 = 0.f, a7 = 0.f;
    int j = j0;
    for (; j + 4 <= j1; j += 4) {
        uint p0 = ep[j], p1 = ep[j + 1], p2 = ep[j + 2], p3 = ep[j + 3];
        uint4 u0 = *reinterpret_cast<const uint4*>(yb + (size_t)(p0 & 0xffffu) * 64 + c * 4);
        uint4 u1 = *reinterpret_cast<const uint4*>(yb + (size_t)(p1 & 0xffffu) * 64 + c * 4);
        uint4 u2 = *reinterpret_cast<const uint4*>(yb + (size_t)(p2 & 0xffffu) * 64 + c * 4);
        uint4 u3 = *reinterpret_cast<const uint4*>(yb + (size_t)(p3 & 0xffffu) * 64 + c * 4);
        float v0 = __uint_as_float(p0 & 0xffff0000u);
        float v1 = __uint_as_float(p1 & 0xffff0000u);
        float v2 = __uint_as_float(p2 & 0xffff0000u);
        float v3 = __uint_as_float(p3 & 0xffff0000u);
        a0 += v0 * bflo(u0.x) + v1 * bflo(u1.x) + v2 * bflo(u2.x) + v3 * bflo(u3.x);
        a1 += v0 * bfhi(u0.x) + v1 * bfhi(u1.x) + v2 * bfhi(u2.x) + v3 * bfhi(u3.x);
        a2 += v0 * bflo(u0.y) + v1 * bflo(u1.y) + v2 * bflo(u2.y) + v3 * bflo(u3.y);
        a3 += v0 * bfhi(u0.y) + v1 * bfhi(u1.y) + v2 * bfhi(u2.y) + v3 * bfhi(u3.y);
        a4 += v0 * bflo(u0.z) + v1 * bflo(u1.z) + v2 * bflo(u2.z) + v3 * bflo(u3.z);
        a5 += v0 * bfhi(u0.z) + v1 * bfhi(u1.z) + v2 * bfhi(u2.z) + v3 * bfhi(u3.z);
        a6 += v0 * bflo(u0.w) + v1 * bflo(u1.w) + v2 * bflo(u2.w) + v3 * bflo(u3.w);
        a7 += v0 * bfhi(u0.w) + v1 * bfhi(u1.w) + v2 * bfhi(u2.w) + v3 * bfhi(u3.w);
    }
    for (; j < j1; ++j) {
        uint p = ep[j];
        uint4 u = *reinterpret_cast<const uint4*>(yb + (size_t)(p & 0xffffu) * 64 + c * 4);
        float v = __uint_as_float(p & 0xffff0000u);
        a0 += v * bflo(u.x); a1 += v * bfhi(u.x);
        a2 += v * bflo(u.y); a3 += v * bfhi(u.y);
        a4 += v * bflo(u.z); a5 += v * bfhi(u.z);
        a6 += v * bflo(u.w); a7 += v * bfhi(u.w);
    }
    f32x4 r0, r1;
    r0[0] = fmaxf(a0 + bv0.x, 0.f);
    r0[1] = fmaxf(a1 + bv0.y, 0.f);
    r0[2] = fmaxf(a2 + bv0.z, 0.f);
    r0[3] = fmaxf(a3 + bv0.w, 0.f);
    r1[0] = fmaxf(a4 + bv1.x, 0.f);
    r1[1] = fmaxf(a5 + bv1.y, 0.f);
    r1[2] = fmaxf(a6 + bv1.z, 0.f);
    r1[3] = fmaxf(a7 + bv1.w, 0.f);
    f32x4* op = reinterpret_cast<f32x4*>(out + (long)n * D + c * 8);
    __builtin_nontemporal_store(r0, op);
    __builtin_nontemporal_store(r1, op + 1);
}

extern "C" void kernel_launch(void* const* d_in, const int* in_sizes, int n_in,
                              void* d_out, int out_size, void* d_ws, size_t ws_size,
                              hipStream_t stream) {
    const float* x   = (const float*)d_in[0];
    const int*   es  = (const int*)d_in[1];
    const int*   ed  = (const int*)d_in[2];
    const float* ev  = (const float*)d_in[3];
    const float* W   = (const float*)d_in[4];
    const float* b   = (const float*)d_in[5];
    float* out = (float*)d_out;

    // Workspace layout (16B-aligned fields), total ~16.3 MB
    char* ws = (char*)d_ws;
    size_t off = 0;
    uint*   yb     = (uint*)  (ws + off); off += (size_t)N_NODES * (D / 2) * sizeof(uint);   // 12.8 MB
    ushort* Wb     = (ushort*)(ws + off); off += (size_t)D * D * sizeof(ushort);             // 32 KB
    uint*   epack  = (uint*)  (ws + off); off += (size_t)N_EDGES * sizeof(uint);             // 3.2 MB
    int*    rowptr = (int*)   (ws + off); off += ((size_t)(N_NODES + 1) * sizeof(int) + 15) & ~15ull;
    int*    deg    = (int*)   (ws + off); off += (size_t)N_NODES * sizeof(int);
    // rank overlays d_out: rank is dead before sgcn_aggregate (sole writer of out).
    int* rank = (int*)d_out;

    const int EB = (N_EDGES + 255) / 256;  // 3125

    sgcn_prep<<<64, 256, 0, stream>>>(W, Wb, deg);
    sgcn_gemm_y<<<512, 256, 0, stream>>>(x, Wb, (ushort*)yb);

    {
        const int* src_ = es; const int* dst_ = ed; const float* val_ = ev;
        int* deg_ = deg; int* rank_ = rank; int* rowptr_ = rowptr; uint* epack_ = epack;
        void* args[] = {&src_, &dst_, &val_, &deg_, &rank_, &rowptr_, &epack_};
        hipError_t cerr = hipLaunchCooperativeKernel(
            (const void*)sgcn_csr, dim3(1024), dim3(256), args, 0, stream);
        if (cerr != hipSuccess) {
            // Fallback: separate kernels
            sgcn_hist_rank<<<EB, 256, 0, stream>>>(ed, deg, rank);
            sgcn_scanf<<<SCAN_NB, 256, 0, stream>>>(deg, rowptr);
            sgcn_permute<<<EB, 256, 0, stream>>>(es, ed, ev, rowptr, rank, epack);
        }
    }

    sgcn_aggregate<<<3125, 256, 0, stream>>>(yb, rowptr, epack, b, out);
}

// Round 11
// 115.920 us; speedup vs baseline: 2.6685x; 2.6685x over previous
//
#include <hip/hip_runtime.h>
#include <hip/hip_bf16.h>

#define N_NODES 50000
#define N_EDGES 800000
#define D 128
#define SCAN_NB 49  // ceil(50000/1024)

static_assert(N_NODES < 65536, "src must fit in 16 bits for epack");

typedef __attribute__((ext_vector_type(8))) short short8;
typedef __attribute__((ext_vector_type(4))) float f32x4;
typedef unsigned int uint;
typedef unsigned short ushort;

__device__ __forceinline__ ushort f2bf(float f) {
    // float -> bf16 bits, round-to-nearest-even
    uint u = __float_as_uint(f);
    u += 0x7fffu + ((u >> 16) & 1u);
    return (ushort)(u >> 16);
}

__device__ __forceinline__ float bflo(uint u) { return __uint_as_float(u << 16); }
__device__ __forceinline__ float bfhi(uint u) { return __uint_as_float(u & 0xffff0000u); }

// ---------------- prep: W fp32->bf16 AND zero deg (independent work) ----------------

__global__ __launch_bounds__(256) void sgcn_prep(
    const float* __restrict__ W, ushort* __restrict__ Wb, int* __restrict__ deg)
{
    int t = blockIdx.x * 256 + threadIdx.x;
    if (t < (D * D) / 4) {
        float4 a = reinterpret_cast<const float4*>(W)[t];
        ushort4 s;
        s.x = f2bf(a.x); s.y = f2bf(a.y); s.z = f2bf(a.z); s.w = f2bf(a.w);
        *reinterpret_cast<ushort4*>(Wb + (size_t)t * 4) = s;
    }
    if (t < N_NODES / 4) {  // 12500 int4 stores zero 50000 ints exactly
        reinterpret_cast<int4*>(deg)[t] = make_int4(0, 0, 0, 0);
    }
}

// ---------------- CSR build (3 kernels — coop grid.sync measured 10x worse) ----------------

__global__ __launch_bounds__(256) void sgcn_hist_rank(
    const int* __restrict__ dst, int* __restrict__ deg, int* __restrict__ rank)
{
    int e = blockIdx.x * 256 + threadIdx.x;
    if (e < N_EDGES)
        rank[e] = atomicAdd(&deg[dst[e]], 1);
}

// Fused scan: block b computes off0 = sum(deg[0 .. b*1024)) itself (deg is L2-hot),
// then exclusive-scans its own 1024-chunk.
__global__ __launch_bounds__(256) void sgcn_scanf(
    const int* __restrict__ deg, int* __restrict__ rowptr)
{
    __shared__ int part[256];
    __shared__ int soff;
    int tid = threadIdx.x;
    int b = blockIdx.x;

    const int4* d4 = reinterpret_cast<const int4*>(deg);
    int pre = 0;
    for (int i = tid; i < b * 256; i += 256) {
        int4 v = d4[i];
        pre += v.x + v.y + v.z + v.w;
    }
    part[tid] = pre;
    __syncthreads();
    for (int off = 128; off > 0; off >>= 1) {
        if (tid < off) part[tid] += part[tid + off];
        __syncthreads();
    }
    if (tid == 0) soff = part[0];
    __syncthreads();

    int base = b * 1024 + tid * 4;
    int4 v = make_int4(0, 0, 0, 0);
    if (base < N_NODES) v = *reinterpret_cast<const int4*>(deg + base);
    int s = v.x + v.y + v.z + v.w;
    part[tid] = s;
    __syncthreads();
    for (int off = 1; off < 256; off <<= 1) {
        int mine  = part[tid];
        int other = (tid >= off) ? part[tid - off] : 0;
        __syncthreads();
        part[tid] = mine + other;
        __syncthreads();
    }
    int run = soff + ((tid == 0) ? 0 : part[tid - 1]);
    if (base < N_NODES) {
        int4 r;
        r.x = run;
        r.y = run + v.x;
        r.z = r.y + v.y;
        r.w = r.z + v.z;
        *reinterpret_cast<int4*>(rowptr + base) = r;
        if (base + 4 == N_NODES) rowptr[N_NODES] = r.w + v.w;
    }
}

// epack[pos] = (bf16(val) << 16) | src  — 4 bytes per edge.
__global__ __launch_bounds__(256) void sgcn_permute(
    const int* __restrict__ src, const int* __restrict__ dst,
    const float* __restrict__ val, const int* __restrict__ rowptr,
    const int* __restrict__ rank, uint* __restrict__ epack)
{
    int e = blockIdx.x * 256 + threadIdx.x;
    if (e < N_EDGES) {
        int pos = rowptr[dst[e]] + rank[e];
        epack[pos] = ((uint)f2bf(val[e]) << 16) | (uint)src[e];
    }
}

// ---------------- MFMA GEMM first: y = x @ W^T (bf16 out) ----------------
// Wave: 16-row x 128-col stripe. A: lane holds x[m0+(l&15)][kb*8+j] (fp32 read,
// bf16 convert inline). B: lane holds W[nt*16+(l&15)][kb*8+j] (row-major Wb).
// C/D: col = l&15 (n), row = kb*4 + r (m). [m89 layout]

__global__ __launch_bounds__(256) void sgcn_gemm_y(
    const float* __restrict__ x, const ushort* __restrict__ Wb,
    ushort* __restrict__ y)
{
    int wave = threadIdx.x >> 6;
    int lane = threadIdx.x & 63;
    int lm = lane & 15;
    int kb = lane >> 4;

    short8 bfr[8][4];
#pragma unroll
    for (int nt = 0; nt < 8; ++nt)
#pragma unroll
        for (int kk = 0; kk < 4; ++kk)
            bfr[nt][kk] = *reinterpret_cast<const short8*>(
                Wb + (nt * 16 + lm) * D + kk * 32 + kb * 8);

    const int nMT = N_NODES / 16;  // 3125
    int mt0 = blockIdx.x * 4 + wave;
    int strideMT = gridDim.x * 4;
    for (int mt = mt0; mt < nMT; mt += strideMT) {
        int m0 = mt * 16;
        const float* xrow = x + (long)(m0 + lm) * D + kb * 8;
        short8 afr[4];
#pragma unroll
        for (int kk = 0; kk < 4; ++kk) {
            float4 a = *reinterpret_cast<const float4*>(xrow + kk * 32);
            float4 c = *reinterpret_cast<const float4*>(xrow + kk * 32 + 4);
            short8 s;
            s[0] = (short)f2bf(a.x); s[1] = (short)f2bf(a.y);
            s[2] = (short)f2bf(a.z); s[3] = (short)f2bf(a.w);
            s[4] = (short)f2bf(c.x); s[5] = (short)f2bf(c.y);
            s[6] = (short)f2bf(c.z); s[7] = (short)f2bf(c.w);
            afr[kk] = s;
        }
#pragma unroll
        for (int nt = 0; nt < 8; ++nt) {
            f32x4 acc = {0.f, 0.f, 0.f, 0.f};
#pragma unroll
            for (int kk = 0; kk < 4; ++kk)
                acc = __builtin_amdgcn_mfma_f32_16x16x32_bf16(afr[kk], bfr[nt][kk], acc, 0, 0, 0);
            ushort* yp = y + (long)(m0 + kb * 4) * D + nt * 16 + lm;
#pragma unroll
            for (int r = 0; r < 4; ++r)
                yp[(long)r * D] = f2bf(acc[r]);
        }
    }
}

// ---------------- Aggregation: ONE NODE PER QUARTER-WAVE ----------------
// yb rows = 64 uints (256 B). Quarter (16 lanes) owns one node; lane c reads
// uint4 at row*64 + c*4 (channels c*8..c*8+7). No shuffles — each lane's
// accumulators are complete. 4-edge unroll -> 4 rows in flight per quarter
// (16 per wave). 3125 blocks x 16 quarters = 50000 nodes exactly.

__global__ __launch_bounds__(256) void sgcn_aggregate(
    const uint* __restrict__ yb, const int* __restrict__ rowptr,
    const uint* __restrict__ ep, const float* __restrict__ bias,
    float* __restrict__ out)
{
    int n = (blockIdx.x * 256 + threadIdx.x) >> 4;  // exact: grid*16 == N_NODES
    int c = threadIdx.x & 15;
    float4 bv0 = *reinterpret_cast<const float4*>(bias + c * 8);
    float4 bv1 = *reinterpret_cast<const float4*>(bias + c * 8 + 4);

    int j0 = rowptr[n], j1 = rowptr[n + 1];
    float a0 = 0.f, a1 = 0.f, a2 = 0.f, a3 = 0.f;
    float a4 = 0.f, a5 = 0.f, a6 = 0.f, a7 = 0.f;
    int j = j0;
    for (; j + 4 <= j1; j += 4) {
        uint p0 = ep[j], p1 = ep[j + 1], p2 = ep[j + 2], p3 = ep[j + 3];
        uint4 u0 = *reinterpret_cast<const uint4*>(yb + (size_t)(p0 & 0xffffu) * 64 + c * 4);
        uint4 u1 = *reinterpret_cast<const uint4*>(yb + (size_t)(p1 & 0xffffu) * 64 + c * 4);
        uint4 u2 = *reinterpret_cast<const uint4*>(yb + (size_t)(p2 & 0xffffu) * 64 + c * 4);
        uint4 u3 = *reinterpret_cast<const uint4*>(yb + (size_t)(p3 & 0xffffu) * 64 + c * 4);
        float v0 = __uint_as_float(p0 & 0xffff0000u);
        float v1 = __uint_as_float(p1 & 0xffff0000u);
        float v2 = __uint_as_float(p2 & 0xffff0000u);
        float v3 = __uint_as_float(p3 & 0xffff0000u);
        a0 += v0 * bflo(u0.x) + v1 * bflo(u1.x) + v2 * bflo(u2.x) + v3 * bflo(u3.x);
        a1 += v0 * bfhi(u0.x) + v1 * bfhi(u1.x) + v2 * bfhi(u2.x) + v3 * bfhi(u3.x);
        a2 += v0 * bflo(u0.y) + v1 * bflo(u1.y) + v2 * bflo(u2.y) + v3 * bflo(u3.y);
        a3 += v0 * bfhi(u0.y) + v1 * bfhi(u1.y) + v2 * bfhi(u2.y) + v3 * bfhi(u3.y);
        a4 += v0 * bflo(u0.z) + v1 * bflo(u1.z) + v2 * bflo(u2.z) + v3 * bflo(u3.z);
        a5 += v0 * bfhi(u0.z) + v1 * bfhi(u1.z) + v2 * bfhi(u2.z) + v3 * bfhi(u3.z);
        a6 += v0 * bflo(u0.w) + v1 * bflo(u1.w) + v2 * bflo(u2.w) + v3 * bflo(u3.w);
        a7 += v0 * bfhi(u0.w) + v1 * bfhi(u1.w) + v2 * bfhi(u2.w) + v3 * bfhi(u3.w);
    }
    for (; j < j1; ++j) {
        uint p = ep[j];
        uint4 u = *reinterpret_cast<const uint4*>(yb + (size_t)(p & 0xffffu) * 64 + c * 4);
        float v = __uint_as_float(p & 0xffff0000u);
        a0 += v * bflo(u.x); a1 += v * bfhi(u.x);
        a2 += v * bflo(u.y); a3 += v * bfhi(u.y);
        a4 += v * bflo(u.z); a5 += v * bfhi(u.z);
        a6 += v * bflo(u.w); a7 += v * bfhi(u.w);
    }
    f32x4 r0, r1;
    r0[0] = fmaxf(a0 + bv0.x, 0.f);
    r0[1] = fmaxf(a1 + bv0.y, 0.f);
    r0[2] = fmaxf(a2 + bv0.z, 0.f);
    r0[3] = fmaxf(a3 + bv0.w, 0.f);
    r1[0] = fmaxf(a4 + bv1.x, 0.f);
    r1[1] = fmaxf(a5 + bv1.y, 0.f);
    r1[2] = fmaxf(a6 + bv1.z, 0.f);
    r1[3] = fmaxf(a7 + bv1.w, 0.f);
    f32x4* op = reinterpret_cast<f32x4*>(out + (long)n * D + c * 8);
    __builtin_nontemporal_store(r0, op);
    __builtin_nontemporal_store(r1, op + 1);
}

extern "C" void kernel_launch(void* const* d_in, const int* in_sizes, int n_in,
                              void* d_out, int out_size, void* d_ws, size_t ws_size,
                              hipStream_t stream) {
    const float* x   = (const float*)d_in[0];
    const int*   es  = (const int*)d_in[1];
    const int*   ed  = (const int*)d_in[2];
    const float* ev  = (const float*)d_in[3];
    const float* W   = (const float*)d_in[4];
    const float* b   = (const float*)d_in[5];
    float* out = (float*)d_out;

    // Workspace layout (16B-aligned fields), total ~16.3 MB
    char* ws = (char*)d_ws;
    size_t off = 0;
    uint*   yb     = (uint*)  (ws + off); off += (size_t)N_NODES * (D / 2) * sizeof(uint);   // 12.8 MB
    ushort* Wb     = (ushort*)(ws + off); off += (size_t)D * D * sizeof(ushort);             // 32 KB
    uint*   epack  = (uint*)  (ws + off); off += (size_t)N_EDGES * sizeof(uint);             // 3.2 MB
    int*    rowptr = (int*)   (ws + off); off += ((size_t)(N_NODES + 1) * sizeof(int) + 15) & ~15ull;
    int*    deg    = (int*)   (ws + off); off += (size_t)N_NODES * sizeof(int);
    // rank overlays d_out: rank is dead before sgcn_aggregate (sole writer of out).
    int* rank = (int*)d_out;

    const int EB = (N_EDGES + 255) / 256;  // 3125

    sgcn_prep<<<64, 256, 0, stream>>>(W, Wb, deg);
    sgcn_gemm_y<<<512, 256, 0, stream>>>(x, Wb, (ushort*)yb);
    sgcn_hist_rank<<<EB, 256, 0, stream>>>(ed, deg, rank);
    sgcn_scanf<<<SCAN_NB, 256, 0, stream>>>(deg, rowptr);
    sgcn_permute<<<EB, 256, 0, stream>>>(es, ed, ev, rowptr, rank, epack);
    sgcn_aggregate<<<3125, 256, 0, stream>>>(yb, rowptr, epack, b, out);
}